// Round 10
// baseline (2852.218 us; speedup 1.0000x reference)
//
#include <hip/hip_runtime.h>
#include <math.h>

#define B_ 16
#define T_ 4096
#define D_ 512
#define T1_ 4097
#define NTHR 1024      // 16 waves, 4/SIMD, 1 block/CU

#define SMOOTH_FACTOR 1.0
#define NOISE_THRESHOLD 0.0
#define TAIL_THRESHOLD 0.45

typedef short bf16x8 __attribute__((ext_vector_type(8)));
typedef float f32x16 __attribute__((ext_vector_type(16)));
union U4 { uint4 u; bf16x8 s; };

// ---- workspace layout (bytes) ----
#define WB_OFF   ((size_t)0)         // bf16 W frags: 2*96*2*512*8*2 = 3145728
#define A64_OFF  ((size_t)3145728)   // f64 alpha[b][T1]: 524416
#define FT_OFF   ((size_t)3670144)   // i32 fire_t[b][T1]: 262208
#define FF_OFF   ((size_t)3932352)   // f64 fire_frac[b][T1]: 524416
#define LEN_OFF  ((size_t)4456768)   // i32 batch_len[b]: 64

__device__ __forceinline__ unsigned bf_rne(unsigned x) {
    return (x + 0x7FFFu + ((x >> 16) & 1u)) >> 16;
}

// ============ K0: conv_w [o][i][k] f32 -> bf16 hi/mid fragment stream ============
// wb uint4 index = ((comp*96 + c)*2 + kg)*512 + o ; k = c*16 + kg*8 + e;
// tap = k>>9; i = k&511.  (unchanged)
__global__ void k_wt(const float* __restrict__ cw, uint4* __restrict__ wb) {
    int idx = blockIdx.x * 256 + threadIdx.x;
    if (idx >= 196608) return;
    int o  = idx & 511;
    int r  = idx >> 9;
    int kg = r & 1;
    int rc = r >> 1;
    int comp = rc / 96;
    int c    = rc - comp * 96;
    unsigned uw[4];
    #pragma unroll
    for (int j = 0; j < 4; ++j) {
        unsigned short us[2];
        #pragma unroll
        for (int q = 0; q < 2; ++q) {
            int e = j * 2 + q;
            int k = c * 16 + kg * 8 + e;
            int tap = k >> 9, i = k & 511;
            float v = cw[((size_t)o * D_ + i) * 3 + tap];
            unsigned x  = __float_as_uint(v);
            unsigned hi = bf_rne(x);
            if (comp == 0) us[q] = (unsigned short)hi;
            else {
                float rem = v - __uint_as_float(hi << 16);
                us[q] = (unsigned short)bf_rne(__float_as_uint(rem));
            }
        }
        uw[j] = (unsigned)us[0] | ((unsigned)us[1] << 16);
    }
    wb[idx] = make_uint4(uw[0], uw[1], uw[2], uw[3]);
}

// ============ K1: 3-product bf16-split MFMA conv, t=256, 16 waves (8 og x 2 tg) ======
// grid (T_/256, B_) = 256 blocks (1/CU), 1024 thr. Wave (og,tg): o in [og*64,+64)
// (2 tiles), t in [t0+tg*128,+128) (4 subs). acc = 8 x f32x16 = 128 AGPR.
// A in LDS, four i-phases of [258][17] uint4 x2 (140 KB). W dbuf from L2.
// Per chunk/CU: MFMA 3072 cyc; W-L2 21 B/cyc (37%); A-LDS 42 B/cyc (50%).
__global__ __launch_bounds__(NTHR)
void k_conv(const float* __restrict__ h, const uint4* __restrict__ wb,
            const float* __restrict__ cbp, const float* __restrict__ owp,
            const float* __restrict__ mask, const float* __restrict__ obp,
            float* __restrict__ out_alpha, double* __restrict__ a64) {
    extern __shared__ uint4 lds[];
    uint4* Ahi = lds;              // [258][17] uint4
    uint4* Ami = lds + 258 * 17;

    const int tid  = threadIdx.x;
    const int b    = blockIdx.y;
    const int t0   = blockIdx.x * 256;
    const int lane = tid & 63;
    const int w    = tid >> 6;        // 0..15
    const int l31  = lane & 31;
    const int kg   = lane >> 5;
    const int og   = w >> 1;          // 0..7
    const int tg   = w & 1;           // 0..1

    const float* hb = h + (size_t)b * T_ * D_;

    f32x16 c00 = {0,0,0,0,0,0,0,0,0,0,0,0,0,0,0,0};
    f32x16 c01 = c00, c10 = c00, c11 = c00, c20 = c00, c21 = c00, c30 = c00, c31 = c00;

    // W pointers: index = comp*98304 + c*1024 + kg*512 + o
    const uint4* wph0 = wb + ((size_t)kg * 512 + og * 64 + l31);
    const uint4* wph1 = wph0 + 32;
    const uint4* wpm0 = wph0 + 98304;
    const uint4* wpm1 = wph1 + 98304;

    U4 wAh0, wAh1, wAm0, wAm1, wBh0, wBh1, wBm0, wBm1;
    U4 ah0, am0, ah1, am1, ah2, am2, ah3, am3;

    // chunk id: phase PH (i in [PH*128,+128)), in-phase QQ 0..23, tap = QQ>>3
    #define LOADW(C, H0, H1, M0, M1) { size_t c_ = (size_t)(C) * 1024;  \
        H0.u = wph0[c_]; H1.u = wph1[c_];                               \
        M0.u = wpm0[c_]; M1.u = wpm1[c_]; }
    #define LOADWG(PH, QQ, H0, H1, M0, M1) { int p_ = (PH), q_ = (QQ);  \
        if (q_ >= 24) { p_++; q_ -= 24; }                               \
        if (p_ < 4) LOADW((((q_ >> 3) << 5) + p_ * 8 + (q_ & 7)), H0, H1, M0, M1); }

    #define LOADA(QQ) {                                                         \
        int ia_ = (tg * 128 + l31 + ((QQ) >> 3)) * 17 + (((QQ) & 7) << 1) + kg; \
        ah0.u = Ahi[ia_];            am0.u = Ami[ia_];                          \
        ah1.u = Ahi[ia_ + 32 * 17];  am1.u = Ami[ia_ + 32 * 17];                \
        ah2.u = Ahi[ia_ + 64 * 17];  am2.u = Ami[ia_ + 64 * 17];                \
        ah3.u = Ahi[ia_ + 96 * 17];  am3.u = Ami[ia_ + 96 * 17]; }

    #define MF3(AH, AM, CC, WH, WM) {                                           \
        CC = __builtin_amdgcn_mfma_f32_32x32x16_bf16(AH.s, WH.s, CC, 0, 0, 0);  \
        CC = __builtin_amdgcn_mfma_f32_32x32x16_bf16(AH.s, WM.s, CC, 0, 0, 0);  \
        CC = __builtin_amdgcn_mfma_f32_32x32x16_bf16(AM.s, WH.s, CC, 0, 0, 0); }

    #define MFMA24(H0, H1, M0, M1) {                                 \
        MF3(ah0, am0, c00, H0, M0);  MF3(ah0, am0, c01, H1, M1);     \
        MF3(ah1, am1, c10, H0, M0);  MF3(ah1, am1, c11, H1, M1);     \
        MF3(ah2, am2, c20, H0, M0);  MF3(ah2, am2, c21, H1, M1);     \
        MF3(ah3, am3, c30, H0, M0);  MF3(ah3, am3, c31, H1, M1); }

    LOADWG(0, 0, wAh0, wAh1, wAm0, wAm1);
    LOADWG(0, 1, wBh0, wBh1, wBm0, wBm1);

    for (int ph = 0; ph < 4; ++ph) {
        if (ph) __syncthreads();          // all reads of previous phase done
        // ---- stage A cols [ph*128,+128) rows t0-1..t0+256, pipelined, -> bf16 hi/mi ----
        {
            float4 x0, x1, y0, y1;
            int idx = tid;
            {   // preload first item
                int r = idx >> 4, cj = idx & 15, t = t0 - 1 + r;
                if (t >= 0 && t < T_) {
                    const float* p = hb + (size_t)t * D_ + ph * 128 + cj * 8;
                    x0 = *(const float4*)p; x1 = *(const float4*)(p + 4);
                } else { x0 = x1 = make_float4(0.f, 0.f, 0.f, 0.f); }
            }
            for (int it = 0; it < 5; ++it) {
                int nidx = idx + NTHR;
                if (it < 4 && nidx < 4128) {
                    int r = nidx >> 4, cj = nidx & 15, t = t0 - 1 + r;
                    if (t >= 0 && t < T_) {
                        const float* p = hb + (size_t)t * D_ + ph * 128 + cj * 8;
                        y0 = *(const float4*)p; y1 = *(const float4*)(p + 4);
                    } else { y0 = y1 = make_float4(0.f, 0.f, 0.f, 0.f); }
                }
                if (idx < 4128) {
                    float v[8] = {x0.x, x0.y, x0.z, x0.w, x1.x, x1.y, x1.z, x1.w};
                    unsigned hw[4], mw[4];
                    #pragma unroll
                    for (int j = 0; j < 4; ++j) {
                        unsigned short hs_[2], ms_[2];
                        #pragma unroll
                        for (int q = 0; q < 2; ++q) {
                            float f = v[j * 2 + q];
                            unsigned hi = bf_rne(__float_as_uint(f));
                            float rem = f - __uint_as_float(hi << 16);
                            hs_[q] = (unsigned short)hi;
                            ms_[q] = (unsigned short)bf_rne(__float_as_uint(rem));
                        }
                        hw[j] = hs_[0] | ((unsigned)hs_[1] << 16);
                        mw[j] = ms_[0] | ((unsigned)ms_[1] << 16);
                    }
                    int r = idx >> 4, cj = idx & 15;
                    Ahi[r * 17 + cj] = make_uint4(hw[0], hw[1], hw[2], hw[3]);
                    Ami[r * 17 + cj] = make_uint4(mw[0], mw[1], mw[2], mw[3]);
                }
                x0 = y0; x1 = y1; idx = nidx;
            }
        }
        __syncthreads();

        for (int qq = 0; qq < 24; qq += 2) {
            LOADA(qq);
            MFMA24(wAh0, wAh1, wAm0, wAm1);
            LOADWG(ph, qq + 2, wAh0, wAh1, wAm0, wAm1);
            LOADA(qq + 1);
            MFMA24(wBh0, wBh1, wBm0, wBm1);
            LOADWG(ph, qq + 3, wBh0, wBh1, wBm0, wBm1);
        }
    }
    #undef LOADW
    #undef LOADWG
    #undef LOADA
    #undef MF3
    #undef MFMA24

    // ---- epilogue: f64 relu-dot over wave's 64 o -> pw[8 og][256 t] -> fused alpha ----
    const int o0 = og * 64 + l31, o1 = o0 + 32;
    const double cb0 = (double)cbp[o0], cb1 = (double)cbp[o1];
    const double ow0 = (double)owp[o0], ow1 = (double)owp[o1];
    __syncthreads();                      // all LDS A reads done; safe to overlay
    double* pw = (double*)lds;            // [8][256] f64 = 16 KB

    #pragma unroll
    for (int s = 0; s < 4; ++s) {
        const f32x16 aa = (s == 0) ? c00 : (s == 1) ? c10 : (s == 2) ? c20 : c30;
        const f32x16 ab = (s == 0) ? c01 : (s == 1) ? c11 : (s == 2) ? c21 : c31;
        #pragma unroll
        for (int v = 0; v < 16; ++v) {
            double z0 = (double)aa[v] + cb0; z0 = z0 > 0.0 ? z0 : 0.0;
            double z1 = (double)ab[v] + cb1; z1 = z1 > 0.0 ? z1 : 0.0;
            double p = fma(ow0, z0, ow1 * z1);
            #pragma unroll
            for (int off = 1; off < 32; off <<= 1) p += __shfl_xor(p, off);
            if (l31 == 0) {
                int m = (v & 3) + 8 * (v >> 2) + 4 * kg;
                pw[og * 256 + tg * 128 + s * 32 + m] = p;
            }
        }
    }
    __syncthreads();

    if (tid < 256) {
        int t = t0 + tid;
        double osum = (double)obp[0];
        #pragma unroll
        for (int j = 0; j < 8; ++j) osum += pw[j * 256 + tid];
        double sg = 1.0 / (1.0 + exp(-osum));
        double ap = sg * SMOOTH_FACTOR - NOISE_THRESHOLD;
        if (ap < 0.0) ap = 0.0;
        double mk = (double)mask[b * T_ + t];
        double mprev = (t == 0) ? 1.0 : (double)mask[b * T_ + t - 1];
        double a = ap * mk + TAIL_THRESHOLD * (mprev - mk);
        out_alpha[(size_t)b * T1_ + t] = (float)a;
        a64[(size_t)b * T1_ + t] = a;
    }
}

// ============ K2: per-batch wave prefix-scan + fire records (handles t=T tail) ======
__global__ void k_scan(const double* __restrict__ a64, const float* __restrict__ mask,
                       float* __restrict__ out_tok, float* __restrict__ out_alpha,
                       int* __restrict__ fire_t, double* __restrict__ fire_frac,
                       int* __restrict__ blen) {
    const int b = blockIdx.x;
    const int lane = threadIdx.x;
    const double* ab = a64 + (size_t)b * T1_;
    double carry = 0.0;
    int nf = 0;

    double a = ab[lane];   // chunk 0 (t<T_ for all lanes)
    for (int c = 0; c < 65; ++c) {
        int t = c * 64 + lane;
        if (t == T_) {     // tail element computed locally
            a = TAIL_THRESHOLD * (double)mask[b * T_ + T_ - 1];
            out_alpha[(size_t)b * T1_ + T_] = (float)a;
        } else if (t > T_) {
            a = 0.0;
        }
        int tn = t + 64;
        double anext = (tn < T_) ? ab[tn] : 0.0;
        double x = a;
        #pragma unroll
        for (int off = 1; off < 64; off <<= 1) {
            double y = __shfl_up(x, off);
            if (lane >= off) x += y;
        }
        double ps = carry + x;
        double ps_prev = __shfl_up(ps, 1);
        if (lane == 0) ps_prev = carry;
        double psf = floor(ps), ppsf = floor(ps_prev);
        bool fire = (t <= T_) && (psf > ppsf);
        unsigned long long m = __ballot(fire);
        if (fire) {
            int k = nf + (int)__popcll(m & ((1ull << lane) - 1ull));
            fire_t[(size_t)b * T1_ + k] = t;
            fire_frac[(size_t)b * T1_ + k] = ps - psf;
        }
        nf += (int)__popcll(m);
        carry = __shfl(ps, 63);
        a = anext;
    }
    if (lane == 0) {
        blen[b] = nf;
        out_tok[b] = (float)floor(carry);
    }
}

// ============ K3: frame construction (f64 accumulate) ============
__global__ void k_frames(const float* __restrict__ h, const double* __restrict__ a64,
                         const int* __restrict__ fire_t, const double* __restrict__ fire_frac,
                         const int* __restrict__ blen, float* __restrict__ out, int K) {
    const int k = blockIdx.x;
    const int b = blockIdx.y;
    const int tid = threadIdx.x;
    double ax = 0.0, ay = 0.0, az = 0.0, aw = 0.0;
    const int len = blen[b];
    if (k < len) {
        const int t1 = fire_t[(size_t)b * T1_ + k];
        const int t0 = (k > 0) ? fire_t[(size_t)b * T1_ + k - 1] : -1;
        const double f1 = fire_frac[(size_t)b * T1_ + k];
        const double f0 = (k > 0) ? fire_frac[(size_t)b * T1_ + k - 1] : 0.0;
        if (t0 >= 0 && t0 < T_) {
            float4 hv = *(const float4*)(h + ((size_t)b * T_ + t0) * D_ + (tid << 2));
            ax = fma(f0, (double)hv.x, ax); ay = fma(f0, (double)hv.y, ay);
            az = fma(f0, (double)hv.z, az); aw = fma(f0, (double)hv.w, aw);
        }
        for (int t = t0 + 1; t <= t1; ++t) {
            if (t >= T_) break;
            double c = a64[(size_t)b * T1_ + t] - ((t == t1) ? f1 : 0.0);
            float4 hv = *(const float4*)(h + ((size_t)b * T_ + t) * D_ + (tid << 2));
            ax = fma(c, (double)hv.x, ax); ay = fma(c, (double)hv.y, ay);
            az = fma(c, (double)hv.z, az); aw = fma(c, (double)hv.w, aw);
        }
    }
    float4 o = make_float4((float)ax, (float)ay, (float)az, (float)aw);
    *(float4*)(out + ((size_t)b * K + k) * D_ + (tid << 2)) = o;
}

// ============ host ============
extern "C" void kernel_launch(void* const* d_in, const int* in_sizes, int n_in,
                              void* d_out, int out_size, void* d_ws, size_t ws_size,
                              hipStream_t stream) {
    const float* h    = (const float*)d_in[0];
    const float* mask = (const float*)d_in[1];
    const float* cw   = (const float*)d_in[2];
    const float* cb   = (const float*)d_in[3];
    const float* ow   = (const float*)d_in[4];
    const float* ob   = (const float*)d_in[5];

    char* ws = (char*)d_ws;
    uint4*  wb        = (uint4*)(ws + WB_OFF);
    double* a64       = (double*)(ws + A64_OFF);
    int*    fire_t    = (int*)(ws + FT_OFF);
    double* fire_frac = (double*)(ws + FF_OFF);
    int*    blen      = (int*)(ws + LEN_OFF);

    long long K = ((long long)out_size - B_ - (long long)B_ * T1_) / ((long long)B_ * D_);
    if (K < 1) K = 1;
    float* out_ac    = (float*)d_out;
    float* out_tok   = out_ac + (size_t)B_ * K * D_;
    float* out_alpha = out_tok + B_;

    const int lds = 2 * 258 * 17 * 16;   // 140352 B -> 1 block/CU, 16 waves
    (void)hipFuncSetAttribute((const void*)k_conv,
                              hipFuncAttributeMaxDynamicSharedMemorySize, lds);

    k_wt<<<dim3(768), dim3(256), 0, stream>>>(cw, wb);
    k_conv<<<dim3(T_ / 256, B_), dim3(NTHR), lds, stream>>>(h, wb, cb, ow, mask, ob,
                                                            out_alpha, a64);
    k_scan<<<dim3(B_), dim3(64), 0, stream>>>(a64, mask, out_tok, out_alpha,
                                              fire_t, fire_frac, blen);
    k_frames<<<dim3((unsigned)K, B_), dim3(128), 0, stream>>>(h, a64, fire_t, fire_frac,
                                                              blen, out_ac, (int)K);
}

// Round 11
// 337.888 us; speedup vs baseline: 8.4413x; 8.4413x over previous
//
#include <hip/hip_runtime.h>
#include <math.h>

#define B_ 16
#define T_ 4096
#define D_ 512
#define T1_ 4097
#define NTHR 512       // 8 waves, 2/SIMD, 256 regs/wave budget

#define SMOOTH_FACTOR 1.0
#define NOISE_THRESHOLD 0.0
#define TAIL_THRESHOLD 0.45

typedef short bf16x8 __attribute__((ext_vector_type(8)));
typedef float f32x16 __attribute__((ext_vector_type(16)));
union U4 { uint4 u; bf16x8 s; };

// ---- workspace layout (bytes) ----
#define WB_OFF   ((size_t)0)         // bf16 W frags: 2*96*2*512*8*2 = 3145728
#define A64_OFF  ((size_t)3145728)   // f64 alpha[b][T1]: 524416
#define FT_OFF   ((size_t)3670144)   // i32 fire_t[b][T1]: 262208
#define FF_OFF   ((size_t)3932352)   // f64 fire_frac[b][T1]: 524416
#define LEN_OFF  ((size_t)4456768)   // i32 batch_len[b]: 64

__device__ __forceinline__ unsigned bf_rne(unsigned x) {
    return (x + 0x7FFFu + ((x >> 16) & 1u)) >> 16;
}

// ============ K0: conv_w [o][i][k] f32 -> bf16 hi/mid fragment stream ============
// wb uint4 index = ((comp*96 + c)*2 + kg)*512 + o ; k = c*16 + kg*8 + e;
// tap = k>>9; i = k&511.
__global__ void k_wt(const float* __restrict__ cw, uint4* __restrict__ wb) {
    int idx = blockIdx.x * 256 + threadIdx.x;
    if (idx >= 196608) return;
    int o  = idx & 511;
    int r  = idx >> 9;
    int kg = r & 1;
    int rc = r >> 1;
    int comp = rc / 96;
    int c    = rc - comp * 96;
    unsigned uw[4];
    #pragma unroll
    for (int j = 0; j < 4; ++j) {
        unsigned short us[2];
        #pragma unroll
        for (int q = 0; q < 2; ++q) {
            int e = j * 2 + q;
            int k = c * 16 + kg * 8 + e;
            int tap = k >> 9, i = k & 511;
            float v = cw[((size_t)o * D_ + i) * 3 + tap];
            unsigned x  = __float_as_uint(v);
            unsigned hi = bf_rne(x);
            if (comp == 0) us[q] = (unsigned short)hi;
            else {
                float rem = v - __uint_as_float(hi << 16);
                us[q] = (unsigned short)bf_rne(__float_as_uint(rem));
            }
        }
        uw[j] = (unsigned)us[0] | ((unsigned)us[1] << 16);
    }
    wb[idx] = make_uint4(uw[0], uw[1], uw[2], uw[3]);
}

// ============ K1: 3-product bf16-split MFMA conv, t=128 (R7 core) + fused alpha ======
// grid (T_/128, B_), 512 thr (8 waves). Wave w: o in [w*64,+64), t-rows t0..t0+127.
// Per chunk: 24 MFMA. A01 + W double-buffered one chunk ahead; A23 JIT.
// Epilogue: pw[8 og][128 t] LDS overlay -> sigmoid/mask/tail -> a64/out_alpha.
__global__ __launch_bounds__(NTHR)
void k_conv(const float* __restrict__ h, const uint4* __restrict__ wb,
            const float* __restrict__ cbp, const float* __restrict__ owp,
            const float* __restrict__ mask, const float* __restrict__ obp,
            float* __restrict__ out_alpha, double* __restrict__ a64) {
    extern __shared__ uint4 lds[];
    uint4* Ahi = lds;              // [130][33] uint4
    uint4* Ami = lds + 130 * 33;

    const int tid  = threadIdx.x;
    const int b    = blockIdx.y;
    const int t0   = blockIdx.x * 128;
    const int lane = tid & 63;
    const int w    = tid >> 6;
    const int l31  = lane & 31;
    const int kg   = lane >> 5;

    const float* hb = h + (size_t)b * T_ * D_;

    f32x16 c0a = {0,0,0,0,0,0,0,0,0,0,0,0,0,0,0,0};
    f32x16 c0b = c0a, c1a = c0a, c1b = c0a, c2a = c0a, c2b = c0a, c3a = c0a, c3b = c0a;

    const uint4* wp0h = wb + ((size_t)kg * 512 + w * 64 + l31);   // comp0, ot0
    const uint4* wp1h = wp0h + 32;                                 // comp0, ot1
    const uint4* wp0m = wp0h + 98304;                              // comp1, ot0
    const uint4* wp1m = wp1h + 98304;                              // comp1, ot1

    U4 w0hA, w1hA, w0mA, w1mA, w0hB, w1hB, w0mB, w1mB;
    U4 ah0A, am0A, ah1A, am1A, ah0B, am0B, ah1B, am1B;
    U4 ah2, am2, ah3, am3;

    #define LOADW(PH, Q, W0H, W1H, W0M, W1M) {                                   \
        size_t c_ = (size_t)((((Q) >> 4) << 5) + (PH) * 16 + ((Q) & 15)) * 1024; \
        W0H.u = wp0h[c_];  W1H.u = wp1h[c_];                                     \
        W0M.u = wp0m[c_];  W1M.u = wp1m[c_]; }

    #define LOADA01(Q, AH0, AM0, AH1, AM1) {                       \
        int ia_ = (l31 + ((Q) >> 4)) * 33 + (((Q) & 15) << 1) + kg; \
        AH0.u = Ahi[ia_];            AM0.u = Ami[ia_];             \
        AH1.u = Ahi[ia_ + 32 * 33];  AM1.u = Ami[ia_ + 32 * 33]; }

    #define LOADA23(Q) {                                            \
        int ia_ = (l31 + ((Q) >> 4)) * 33 + (((Q) & 15) << 1) + kg; \
        ah2.u = Ahi[ia_ + 64 * 33];  am2.u = Ami[ia_ + 64 * 33];   \
        ah3.u = Ahi[ia_ + 96 * 33];  am3.u = Ami[ia_ + 96 * 33]; }

    #define MF3(AH, AM, CA, CB, W0H, W1H, W0M, W1M) {                             \
        CA = __builtin_amdgcn_mfma_f32_32x32x16_bf16(AH.s, W0H.s, CA, 0, 0, 0);   \
        CB = __builtin_amdgcn_mfma_f32_32x32x16_bf16(AH.s, W1H.s, CB, 0, 0, 0);   \
        CA = __builtin_amdgcn_mfma_f32_32x32x16_bf16(AH.s, W0M.s, CA, 0, 0, 0);   \
        CB = __builtin_amdgcn_mfma_f32_32x32x16_bf16(AH.s, W1M.s, CB, 0, 0, 0);   \
        CA = __builtin_amdgcn_mfma_f32_32x32x16_bf16(AM.s, W0H.s, CA, 0, 0, 0);   \
        CB = __builtin_amdgcn_mfma_f32_32x32x16_bf16(AM.s, W1H.s, CB, 0, 0, 0); }

    LOADW(0, 0, w0hA, w1hA, w0mA, w1mA);   // first chunk's W (no LDS dep)

    for (int ph = 0; ph < 2; ++ph) {
        if (ph) __syncthreads();
        // ---- stage A cols [ph*256,+256) rows t0-1..t0+128, pipelined loads ----
        {
            float4 x0, x1, y0, y1;
            int idx = tid;
            {   // prefetch it=0
                int r = idx >> 5, cu4 = idx & 31, t = t0 - 1 + r;
                if (t >= 0 && t < T_) {
                    const float* p = hb + (size_t)t * D_ + ph * 256 + cu4 * 8;
                    x0 = *(const float4*)p; x1 = *(const float4*)(p + 4);
                } else { x0 = x1 = make_float4(0.f, 0.f, 0.f, 0.f); }
            }
            for (int it = 0; it < 9; ++it) {
                int nidx = idx + 512;
                if (it < 8 && nidx < 4160) {
                    int r = nidx >> 5, cu4 = nidx & 31, t = t0 - 1 + r;
                    if (t >= 0 && t < T_) {
                        const float* p = hb + (size_t)t * D_ + ph * 256 + cu4 * 8;
                        y0 = *(const float4*)p; y1 = *(const float4*)(p + 4);
                    } else { y0 = y1 = make_float4(0.f, 0.f, 0.f, 0.f); }
                }
                if (idx < 4160) {
                    float v[8] = {x0.x, x0.y, x0.z, x0.w, x1.x, x1.y, x1.z, x1.w};
                    unsigned hw[4], mw[4];
                    #pragma unroll
                    for (int j = 0; j < 4; ++j) {
                        unsigned short hs_[2], ms_[2];
                        #pragma unroll
                        for (int q = 0; q < 2; ++q) {
                            float f = v[j * 2 + q];
                            unsigned hi = bf_rne(__float_as_uint(f));
                            float rem = f - __uint_as_float(hi << 16);
                            hs_[q] = (unsigned short)hi;
                            ms_[q] = (unsigned short)bf_rne(__float_as_uint(rem));
                        }
                        hw[j] = hs_[0] | ((unsigned)hs_[1] << 16);
                        mw[j] = ms_[0] | ((unsigned)ms_[1] << 16);
                    }
                    int r = idx >> 5, cu4 = idx & 31;
                    Ahi[r * 33 + cu4] = make_uint4(hw[0], hw[1], hw[2], hw[3]);
                    Ami[r * 33 + cu4] = make_uint4(mw[0], mw[1], mw[2], mw[3]);
                }
                x0 = y0; x1 = y1; idx = nidx;
            }
        }
        __syncthreads();

        LOADA01(0, ah0A, am0A, ah1A, am1A);

        for (int q = 0; q < 48; q += 2) {
            // ---- even chunk q (regs A) ----
            LOADA23(q);
            LOADW(ph, q + 1, w0hB, w1hB, w0mB, w1mB);
            LOADA01(q + 1, ah0B, am0B, ah1B, am1B);
            MF3(ah0A, am0A, c0a, c0b, w0hA, w1hA, w0mA, w1mA);
            MF3(ah1A, am1A, c1a, c1b, w0hA, w1hA, w0mA, w1mA);
            MF3(ah2,  am2,  c2a, c2b, w0hA, w1hA, w0mA, w1mA);
            MF3(ah3,  am3,  c3a, c3b, w0hA, w1hA, w0mA, w1mA);
            // ---- odd chunk q+1 (regs B) ----
            LOADA23(q + 1);
            if (q + 2 < 48) {
                LOADW(ph, q + 2, w0hA, w1hA, w0mA, w1mA);
                LOADA01(q + 2, ah0A, am0A, ah1A, am1A);
            } else if (ph == 0) {
                LOADW(1, 0, w0hA, w1hA, w0mA, w1mA);   // next phase's first W
            }
            MF3(ah0B, am0B, c0a, c0b, w0hB, w1hB, w0mB, w1mB);
            MF3(ah1B, am1B, c1a, c1b, w0hB, w1hB, w0mB, w1mB);
            MF3(ah2,  am2,  c2a, c2b, w0hB, w1hB, w0mB, w1mB);
            MF3(ah3,  am3,  c3a, c3b, w0hB, w1hB, w0mB, w1mB);
        }
    }
    #undef LOADW
    #undef LOADA01
    #undef LOADA23
    #undef MF3

    // ---- epilogue: f64 relu-dot (wave's 64 o) -> pw[8 og][128 t] -> fused alpha ----
    const int o0 = w * 64 + l31, o1 = o0 + 32;
    const double cb0 = (double)cbp[o0], cb1 = (double)cbp[o1];
    const double ow0 = (double)owp[o0], ow1 = (double)owp[o1];
    __syncthreads();                      // all LDS A reads done; safe to overlay
    double* pw = (double*)lds;            // [8][128] f64 = 8 KB

    #pragma unroll
    for (int s = 0; s < 4; ++s) {
        const f32x16 aca = (s == 0) ? c0a : (s == 1) ? c1a : (s == 2) ? c2a : c3a;
        const f32x16 acb = (s == 0) ? c0b : (s == 1) ? c1b : (s == 2) ? c2b : c3b;
        #pragma unroll
        for (int v = 0; v < 16; ++v) {
            double z0 = (double)aca[v] + cb0; z0 = z0 > 0.0 ? z0 : 0.0;
            double z1 = (double)acb[v] + cb1; z1 = z1 > 0.0 ? z1 : 0.0;
            double p = fma(ow0, z0, ow1 * z1);
            #pragma unroll
            for (int off = 1; off < 32; off <<= 1) p += __shfl_xor(p, off);
            if (l31 == 0) {
                int m = (v & 3) + 8 * (v >> 2) + 4 * kg;
                pw[w * 128 + s * 32 + m] = p;
            }
        }
    }
    __syncthreads();

    if (tid < 128) {
        int t = t0 + tid;
        double osum = (double)obp[0];
        #pragma unroll
        for (int j = 0; j < 8; ++j) osum += pw[j * 128 + tid];
        double sg = 1.0 / (1.0 + exp(-osum));
        double ap = sg * SMOOTH_FACTOR - NOISE_THRESHOLD;
        if (ap < 0.0) ap = 0.0;
        double mk = (double)mask[b * T_ + t];
        double mprev = (t == 0) ? 1.0 : (double)mask[b * T_ + t - 1];
        double a = ap * mk + TAIL_THRESHOLD * (mprev - mk);
        out_alpha[(size_t)b * T1_ + t] = (float)a;
        a64[(size_t)b * T1_ + t] = a;
    }
}

// ============ K2: per-batch wave prefix-scan + fire records (handles t=T tail) ======
__global__ void k_scan(const double* __restrict__ a64, const float* __restrict__ mask,
                       float* __restrict__ out_tok, float* __restrict__ out_alpha,
                       int* __restrict__ fire_t, double* __restrict__ fire_frac,
                       int* __restrict__ blen) {
    const int b = blockIdx.x;
    const int lane = threadIdx.x;
    const double* ab = a64 + (size_t)b * T1_;
    double carry = 0.0;
    int nf = 0;

    double a = ab[lane];   // chunk 0 (t<T_ for all lanes)
    for (int c = 0; c < 65; ++c) {
        int t = c * 64 + lane;
        if (t == T_) {     // tail element computed locally
            a = TAIL_THRESHOLD * (double)mask[b * T_ + T_ - 1];
            out_alpha[(size_t)b * T1_ + T_] = (float)a;
        } else if (t > T_) {
            a = 0.0;
        }
        int tn = t + 64;
        double anext = (tn < T_) ? ab[tn] : 0.0;
        double x = a;
        #pragma unroll
        for (int off = 1; off < 64; off <<= 1) {
            double y = __shfl_up(x, off);
            if (lane >= off) x += y;
        }
        double ps = carry + x;
        double ps_prev = __shfl_up(ps, 1);
        if (lane == 0) ps_prev = carry;
        double psf = floor(ps), ppsf = floor(ps_prev);
        bool fire = (t <= T_) && (psf > ppsf);
        unsigned long long m = __ballot(fire);
        if (fire) {
            int k = nf + (int)__popcll(m & ((1ull << lane) - 1ull));
            fire_t[(size_t)b * T1_ + k] = t;
            fire_frac[(size_t)b * T1_ + k] = ps - psf;
        }
        nf += (int)__popcll(m);
        carry = __shfl(ps, 63);
        a = anext;
    }
    if (lane == 0) {
        blen[b] = nf;
        out_tok[b] = (float)floor(carry);
    }
}

// ============ K3: frame construction (f64 accumulate) ============
__global__ void k_frames(const float* __restrict__ h, const double* __restrict__ a64,
                         const int* __restrict__ fire_t, const double* __restrict__ fire_frac,
                         const int* __restrict__ blen, float* __restrict__ out, int K) {
    const int k = blockIdx.x;
    const int b = blockIdx.y;
    const int tid = threadIdx.x;
    double ax = 0.0, ay = 0.0, az = 0.0, aw = 0.0;
    const int len = blen[b];
    if (k < len) {
        const int t1 = fire_t[(size_t)b * T1_ + k];
        const int t0 = (k > 0) ? fire_t[(size_t)b * T1_ + k - 1] : -1;
        const double f1 = fire_frac[(size_t)b * T1_ + k];
        const double f0 = (k > 0) ? fire_frac[(size_t)b * T1_ + k - 1] : 0.0;
        if (t0 >= 0 && t0 < T_) {
            float4 hv = *(const float4*)(h + ((size_t)b * T_ + t0) * D_ + (tid << 2));
            ax = fma(f0, (double)hv.x, ax); ay = fma(f0, (double)hv.y, ay);
            az = fma(f0, (double)hv.z, az); aw = fma(f0, (double)hv.w, aw);
        }
        for (int t = t0 + 1; t <= t1; ++t) {
            if (t >= T_) break;
            double c = a64[(size_t)b * T1_ + t] - ((t == t1) ? f1 : 0.0);
            float4 hv = *(const float4*)(h + ((size_t)b * T_ + t) * D_ + (tid << 2));
            ax = fma(c, (double)hv.x, ax); ay = fma(c, (double)hv.y, ay);
            az = fma(c, (double)hv.z, az); aw = fma(c, (double)hv.w, aw);
        }
    }
    float4 o = make_float4((float)ax, (float)ay, (float)az, (float)aw);
    *(float4*)(out + ((size_t)b * K + k) * D_ + (tid << 2)) = o;
}

// ============ host ============
extern "C" void kernel_launch(void* const* d_in, const int* in_sizes, int n_in,
                              void* d_out, int out_size, void* d_ws, size_t ws_size,
                              hipStream_t stream) {
    const float* h    = (const float*)d_in[0];
    const float* mask = (const float*)d_in[1];
    const float* cw   = (const float*)d_in[2];
    const float* cb   = (const float*)d_in[3];
    const float* ow   = (const float*)d_in[4];
    const float* ob   = (const float*)d_in[5];

    char* ws = (char*)d_ws;
    uint4*  wb        = (uint4*)(ws + WB_OFF);
    double* a64       = (double*)(ws + A64_OFF);
    int*    fire_t    = (int*)(ws + FT_OFF);
    double* fire_frac = (double*)(ws + FF_OFF);
    int*    blen      = (int*)(ws + LEN_OFF);

    long long K = ((long long)out_size - B_ - (long long)B_ * T1_) / ((long long)B_ * D_);
    if (K < 1) K = 1;
    float* out_ac    = (float*)d_out;
    float* out_tok   = out_ac + (size_t)B_ * K * D_;
    float* out_alpha = out_tok + B_;

    const int lds = 2 * 130 * 33 * 16;   // 137280 B
    (void)hipFuncSetAttribute((const void*)k_conv,
                              hipFuncAttributeMaxDynamicSharedMemorySize, lds);

    k_wt<<<dim3(768), dim3(256), 0, stream>>>(cw, wb);
    k_conv<<<dim3(T_ / 128, B_), dim3(NTHR), lds, stream>>>(h, wb, cb, ow, mask, ob,
                                                            out_alpha, a64);
    k_scan<<<dim3(B_), dim3(64), 0, stream>>>(a64, mask, out_tok, out_alpha,
                                              fire_t, fire_frac, blen);
    k_frames<<<dim3((unsigned)K, B_), dim3(128), 0, stream>>>(h, a64, fire_t, fire_frac,
                                                              blen, out_ac, (int)K);
}

// Round 12
// 336.643 us; speedup vs baseline: 8.4725x; 1.0037x over previous
//
#include <hip/hip_runtime.h>
#include <math.h>

#define B_ 16
#define T_ 4096
#define D_ 512
#define T1_ 4097
#define NTHR 512       // 8 waves, 2/SIMD, 256 regs/wave budget

#define SMOOTH_FACTOR 1.0
#define NOISE_THRESHOLD 0.0
#define TAIL_THRESHOLD 0.45

typedef short bf16x8 __attribute__((ext_vector_type(8)));
typedef float f32x16 __attribute__((ext_vector_type(16)));
union U4 { uint4 u; bf16x8 s; };

// ---- workspace layout (bytes) ----
#define WB_OFF   ((size_t)0)         // bf16 W frags: 2*96*2*512*8*2 = 3145728
#define A64_OFF  ((size_t)3145728)   // f64 alpha[b][T1]: 524416
#define FT_OFF   ((size_t)3670144)   // i32 fire_t[b][T1]: 262208
#define FF_OFF   ((size_t)3932352)   // f64 fire_frac[b][T1]: 524416
#define LEN_OFF  ((size_t)4456768)   // i32 batch_len[b]: 64

__device__ __forceinline__ unsigned bf_rne(unsigned x) {
    return (x + 0x7FFFu + ((x >> 16) & 1u)) >> 16;
}

// ============ K0: conv_w [o][i][k] f32 -> bf16 hi/mid fragment stream ============
// wb uint4 index = ((comp*96 + c)*2 + kg)*512 + o ; k = c*16 + kg*8 + e;
// tap = k>>9; i = k&511.
__global__ void k_wt(const float* __restrict__ cw, uint4* __restrict__ wb) {
    int idx = blockIdx.x * 256 + threadIdx.x;
    if (idx >= 196608) return;
    int o  = idx & 511;
    int r  = idx >> 9;
    int kg = r & 1;
    int rc = r >> 1;
    int comp = rc / 96;
    int c    = rc - comp * 96;
    unsigned uw[4];
    #pragma unroll
    for (int j = 0; j < 4; ++j) {
        unsigned short us[2];
        #pragma unroll
        for (int q = 0; q < 2; ++q) {
            int e = j * 2 + q;
            int k = c * 16 + kg * 8 + e;
            int tap = k >> 9, i = k & 511;
            float v = cw[((size_t)o * D_ + i) * 3 + tap];
            unsigned x  = __float_as_uint(v);
            unsigned hi = bf_rne(x);
            if (comp == 0) us[q] = (unsigned short)hi;
            else {
                float rem = v - __uint_as_float(hi << 16);
                us[q] = (unsigned short)bf_rne(__float_as_uint(rem));
            }
        }
        uw[j] = (unsigned)us[0] | ((unsigned)us[1] << 16);
    }
    wb[idx] = make_uint4(uw[0], uw[1], uw[2], uw[3]);
}

// ============ K1: 3-product bf16-split MFMA conv, t=128 + fused alpha ============
// grid (T_/128, B_), 512 thr (8 waves). Wave w: o in [w*64,+64), t-rows t0..t0+127.
// Per chunk: 24 MFMA in THREE PASSES of 8 (same-acc reuse distance 8 = 256 cyc issue,
// vs 2 = 64 cyc in the MF3 order) — per-acc accumulation order unchanged (bitwise id).
__global__ __launch_bounds__(NTHR)
void k_conv(const float* __restrict__ h, const uint4* __restrict__ wb,
            const float* __restrict__ cbp, const float* __restrict__ owp,
            const float* __restrict__ mask, const float* __restrict__ obp,
            float* __restrict__ out_alpha, double* __restrict__ a64) {
    extern __shared__ uint4 lds[];
    uint4* Ahi = lds;              // [130][33] uint4
    uint4* Ami = lds + 130 * 33;

    const int tid  = threadIdx.x;
    const int b    = blockIdx.y;
    const int t0   = blockIdx.x * 128;
    const int lane = tid & 63;
    const int w    = tid >> 6;
    const int l31  = lane & 31;
    const int kg   = lane >> 5;

    const float* hb = h + (size_t)b * T_ * D_;

    f32x16 c0a = {0,0,0,0,0,0,0,0,0,0,0,0,0,0,0,0};
    f32x16 c0b = c0a, c1a = c0a, c1b = c0a, c2a = c0a, c2b = c0a, c3a = c0a, c3b = c0a;

    const uint4* wp0h = wb + ((size_t)kg * 512 + w * 64 + l31);   // comp0, ot0
    const uint4* wp1h = wp0h + 32;                                 // comp0, ot1
    const uint4* wp0m = wp0h + 98304;                              // comp1, ot0
    const uint4* wp1m = wp1h + 98304;                              // comp1, ot1

    U4 w0hA, w1hA, w0mA, w1mA, w0hB, w1hB, w0mB, w1mB;
    U4 ah0A, am0A, ah1A, am1A, ah0B, am0B, ah1B, am1B;
    U4 ah2, am2, ah3, am3;

    #define LOADW(PH, Q, W0H, W1H, W0M, W1M) {                                   \
        size_t c_ = (size_t)((((Q) >> 4) << 5) + (PH) * 16 + ((Q) & 15)) * 1024; \
        W0H.u = wp0h[c_];  W1H.u = wp1h[c_];                                     \
        W0M.u = wp0m[c_];  W1M.u = wp1m[c_]; }

    #define LOADA01(Q, AH0, AM0, AH1, AM1) {                       \
        int ia_ = (l31 + ((Q) >> 4)) * 33 + (((Q) & 15) << 1) + kg; \
        AH0.u = Ahi[ia_];            AM0.u = Ami[ia_];             \
        AH1.u = Ahi[ia_ + 32 * 33];  AM1.u = Ami[ia_ + 32 * 33]; }

    #define LOADA23(Q) {                                            \
        int ia_ = (l31 + ((Q) >> 4)) * 33 + (((Q) & 15) << 1) + kg; \
        ah2.u = Ahi[ia_ + 64 * 33];  am2.u = Ami[ia_ + 64 * 33];   \
        ah3.u = Ahi[ia_ + 96 * 33];  am3.u = Ami[ia_ + 96 * 33]; }

    // One pass: 8 MFMAs touching all 8 accumulators once.
    #define PASS8(A0, A1, A2, A3, W0, W1) {                                        \
        c0a = __builtin_amdgcn_mfma_f32_32x32x16_bf16(A0.s, W0.s, c0a, 0, 0, 0);   \
        c0b = __builtin_amdgcn_mfma_f32_32x32x16_bf16(A0.s, W1.s, c0b, 0, 0, 0);   \
        c1a = __builtin_amdgcn_mfma_f32_32x32x16_bf16(A1.s, W0.s, c1a, 0, 0, 0);   \
        c1b = __builtin_amdgcn_mfma_f32_32x32x16_bf16(A1.s, W1.s, c1b, 0, 0, 0);   \
        c2a = __builtin_amdgcn_mfma_f32_32x32x16_bf16(A2.s, W0.s, c2a, 0, 0, 0);   \
        c2b = __builtin_amdgcn_mfma_f32_32x32x16_bf16(A2.s, W1.s, c2b, 0, 0, 0);   \
        c3a = __builtin_amdgcn_mfma_f32_32x32x16_bf16(A3.s, W0.s, c3a, 0, 0, 0);   \
        c3b = __builtin_amdgcn_mfma_f32_32x32x16_bf16(A3.s, W1.s, c3b, 0, 0, 0); }

    // Chunk = 3 passes: hi*hi, hi*mid, mid*hi  (per-acc order == old MF3 order)
    #define CHUNK24(AH0, AM0, AH1, AM1, W0H, W1H, W0M, W1M) {    \
        PASS8(AH0, AH1, ah2, ah3, W0H, W1H);                     \
        PASS8(AH0, AH1, ah2, ah3, W0M, W1M);                     \
        PASS8(AM0, AM1, am2, am3, W0H, W1H); }

    LOADW(0, 0, w0hA, w1hA, w0mA, w1mA);   // first chunk's W (no LDS dep)

    for (int ph = 0; ph < 2; ++ph) {
        if (ph) __syncthreads();
        // ---- stage A cols [ph*256,+256) rows t0-1..t0+128, pipelined loads ----
        {
            float4 x0, x1, y0, y1;
            int idx = tid;
            {   // prefetch it=0
                int r = idx >> 5, cu4 = idx & 31, t = t0 - 1 + r;
                if (t >= 0 && t < T_) {
                    const float* p = hb + (size_t)t * D_ + ph * 256 + cu4 * 8;
                    x0 = *(const float4*)p; x1 = *(const float4*)(p + 4);
                } else { x0 = x1 = make_float4(0.f, 0.f, 0.f, 0.f); }
            }
            for (int it = 0; it < 9; ++it) {
                int nidx = idx + 512;
                if (it < 8 && nidx < 4160) {
                    int r = nidx >> 5, cu4 = nidx & 31, t = t0 - 1 + r;
                    if (t >= 0 && t < T_) {
                        const float* p = hb + (size_t)t * D_ + ph * 256 + cu4 * 8;
                        y0 = *(const float4*)p; y1 = *(const float4*)(p + 4);
                    } else { y0 = y1 = make_float4(0.f, 0.f, 0.f, 0.f); }
                }
                if (idx < 4160) {
                    float v[8] = {x0.x, x0.y, x0.z, x0.w, x1.x, x1.y, x1.z, x1.w};
                    unsigned hw[4], mw[4];
                    #pragma unroll
                    for (int j = 0; j < 4; ++j) {
                        unsigned short hs_[2], ms_[2];
                        #pragma unroll
                        for (int q = 0; q < 2; ++q) {
                            float f = v[j * 2 + q];
                            unsigned hi = bf_rne(__float_as_uint(f));
                            float rem = f - __uint_as_float(hi << 16);
                            hs_[q] = (unsigned short)hi;
                            ms_[q] = (unsigned short)bf_rne(__float_as_uint(rem));
                        }
                        hw[j] = hs_[0] | ((unsigned)hs_[1] << 16);
                        mw[j] = ms_[0] | ((unsigned)ms_[1] << 16);
                    }
                    int r = idx >> 5, cu4 = idx & 31;
                    Ahi[r * 33 + cu4] = make_uint4(hw[0], hw[1], hw[2], hw[3]);
                    Ami[r * 33 + cu4] = make_uint4(mw[0], mw[1], mw[2], mw[3]);
                }
                x0 = y0; x1 = y1; idx = nidx;
            }
        }
        __syncthreads();

        LOADA01(0, ah0A, am0A, ah1A, am1A);

        for (int q = 0; q < 48; q += 2) {
            // ---- even chunk q (regs A) ----
            LOADA23(q);
            LOADW(ph, q + 1, w0hB, w1hB, w0mB, w1mB);
            LOADA01(q + 1, ah0B, am0B, ah1B, am1B);
            CHUNK24(ah0A, am0A, ah1A, am1A, w0hA, w1hA, w0mA, w1mA);
            // ---- odd chunk q+1 (regs B) ----
            LOADA23(q + 1);
            if (q + 2 < 48) {
                LOADW(ph, q + 2, w0hA, w1hA, w0mA, w1mA);
                LOADA01(q + 2, ah0A, am0A, ah1A, am1A);
            } else if (ph == 0) {
                LOADW(1, 0, w0hA, w1hA, w0mA, w1mA);   // next phase's first W
            }
            CHUNK24(ah0B, am0B, ah1B, am1B, w0hB, w1hB, w0mB, w1mB);
        }
    }
    #undef LOADW
    #undef LOADA01
    #undef LOADA23
    #undef PASS8
    #undef CHUNK24

    // ---- epilogue: f64 relu-dot (wave's 64 o) -> pw[8 og][128 t] -> fused alpha ----
    const int o0 = w * 64 + l31, o1 = o0 + 32;
    const double cb0 = (double)cbp[o0], cb1 = (double)cbp[o1];
    const double ow0 = (double)owp[o0], ow1 = (double)owp[o1];
    __syncthreads();                      // all LDS A reads done; safe to overlay
    double* pw = (double*)lds;            // [8][128] f64 = 8 KB

    #pragma unroll
    for (int s = 0; s < 4; ++s) {
        const f32x16 aca = (s == 0) ? c0a : (s == 1) ? c1a : (s == 2) ? c2a : c3a;
        const f32x16 acb = (s == 0) ? c0b : (s == 1) ? c1b : (s == 2) ? c2b : c3b;
        #pragma unroll
        for (int v = 0; v < 16; ++v) {
            double z0 = (double)aca[v] + cb0; z0 = z0 > 0.0 ? z0 : 0.0;
            double z1 = (double)acb[v] + cb1; z1 = z1 > 0.0 ? z1 : 0.0;
            double p = fma(ow0, z0, ow1 * z1);
            #pragma unroll
            for (int off = 1; off < 32; off <<= 1) p += __shfl_xor(p, off);
            if (l31 == 0) {
                int m = (v & 3) + 8 * (v >> 2) + 4 * kg;
                pw[w * 128 + s * 32 + m] = p;
            }
        }
    }
    __syncthreads();

    if (tid < 128) {
        int t = t0 + tid;
        double osum = (double)obp[0];
        #pragma unroll
        for (int j = 0; j < 8; ++j) osum += pw[j * 128 + tid];
        double sg = 1.0 / (1.0 + exp(-osum));
        double ap = sg * SMOOTH_FACTOR - NOISE_THRESHOLD;
        if (ap < 0.0) ap = 0.0;
        double mk = (double)mask[b * T_ + t];
        double mprev = (t == 0) ? 1.0 : (double)mask[b * T_ + t - 1];
        double a = ap * mk + TAIL_THRESHOLD * (mprev - mk);
        out_alpha[(size_t)b * T1_ + t] = (float)a;
        a64[(size_t)b * T1_ + t] = a;
    }
}

// ============ K2: per-batch wave prefix-scan + fire records (handles t=T tail) ======
__global__ void k_scan(const double* __restrict__ a64, const float* __restrict__ mask,
                       float* __restrict__ out_tok, float* __restrict__ out_alpha,
                       int* __restrict__ fire_t, double* __restrict__ fire_frac,
                       int* __restrict__ blen) {
    const int b = blockIdx.x;
    const int lane = threadIdx.x;
    const double* ab = a64 + (size_t)b * T1_;
    double carry = 0.0;
    int nf = 0;

    double a = ab[lane];   // chunk 0 (t<T_ for all lanes)
    for (int c = 0; c < 65; ++c) {
        int t = c * 64 + lane;
        if (t == T_) {     // tail element computed locally
            a = TAIL_THRESHOLD * (double)mask[b * T_ + T_ - 1];
            out_alpha[(size_t)b * T1_ + T_] = (float)a;
        } else if (t > T_) {
            a = 0.0;
        }
        int tn = t + 64;
        double anext = (tn < T_) ? ab[tn] : 0.0;
        double x = a;
        #pragma unroll
        for (int off = 1; off < 64; off <<= 1) {
            double y = __shfl_up(x, off);
            if (lane >= off) x += y;
        }
        double ps = carry + x;
        double ps_prev = __shfl_up(ps, 1);
        if (lane == 0) ps_prev = carry;
        double psf = floor(ps), ppsf = floor(ps_prev);
        bool fire = (t <= T_) && (psf > ppsf);
        unsigned long long m = __ballot(fire);
        if (fire) {
            int k = nf + (int)__popcll(m & ((1ull << lane) - 1ull));
            fire_t[(size_t)b * T1_ + k] = t;
            fire_frac[(size_t)b * T1_ + k] = ps - psf;
        }
        nf += (int)__popcll(m);
        carry = __shfl(ps, 63);
        a = anext;
    }
    if (lane == 0) {
        blen[b] = nf;
        out_tok[b] = (float)floor(carry);
    }
}

// ============ K3: frame construction (f64 accumulate) ============
__global__ void k_frames(const float* __restrict__ h, const double* __restrict__ a64,
                         const int* __restrict__ fire_t, const double* __restrict__ fire_frac,
                         const int* __restrict__ blen, float* __restrict__ out, int K) {
    const int k = blockIdx.x;
    const int b = blockIdx.y;
    const int tid = threadIdx.x;
    double ax = 0.0, ay = 0.0, az = 0.0, aw = 0.0;
    const int len = blen[b];
    if (k < len) {
        const int t1 = fire_t[(size_t)b * T1_ + k];
        const int t0 = (k > 0) ? fire_t[(size_t)b * T1_ + k - 1] : -1;
        const double f1 = fire_frac[(size_t)b * T1_ + k];
        const double f0 = (k > 0) ? fire_frac[(size_t)b * T1_ + k - 1] : 0.0;
        if (t0 >= 0 && t0 < T_) {
            float4 hv = *(const float4*)(h + ((size_t)b * T_ + t0) * D_ + (tid << 2));
            ax = fma(f0, (double)hv.x, ax); ay = fma(f0, (double)hv.y, ay);
            az = fma(f0, (double)hv.z, az); aw = fma(f0, (double)hv.w, aw);
        }
        for (int t = t0 + 1; t <= t1; ++t) {
            if (t >= T_) break;
            double c = a64[(size_t)b * T1_ + t] - ((t == t1) ? f1 : 0.0);
            float4 hv = *(const float4*)(h + ((size_t)b * T_ + t) * D_ + (tid << 2));
            ax = fma(c, (double)hv.x, ax); ay = fma(c, (double)hv.y, ay);
            az = fma(c, (double)hv.z, az); aw = fma(c, (double)hv.w, aw);
        }
    }
    float4 o = make_float4((float)ax, (float)ay, (float)az, (float)aw);
    *(float4*)(out + ((size_t)b * K + k) * D_ + (tid << 2)) = o;
}

// ============ host ============
extern "C" void kernel_launch(void* const* d_in, const int* in_sizes, int n_in,
                              void* d_out, int out_size, void* d_ws, size_t ws_size,
                              hipStream_t stream) {
    const float* h    = (const float*)d_in[0];
    const float* mask = (const float*)d_in[1];
    const float* cw   = (const float*)d_in[2];
    const float* cb   = (const float*)d_in[3];
    const float* ow   = (const float*)d_in[4];
    const float* ob   = (const float*)d_in[5];

    char* ws = (char*)d_ws;
    uint4*  wb        = (uint4*)(ws + WB_OFF);
    double* a64       = (double*)(ws + A64_OFF);
    int*    fire_t    = (int*)(ws + FT_OFF);
    double* fire_frac = (double*)(ws + FF_OFF);
    int*    blen      = (int*)(ws + LEN_OFF);

    long long K = ((long long)out_size - B_ - (long long)B_ * T1_) / ((long long)B_ * D_);
    if (K < 1) K = 1;
    float* out_ac    = (float*)d_out;
    float* out_tok   = out_ac + (size_t)B_ * K * D_;
    float* out_alpha = out_tok + B_;

    const int lds = 2 * 130 * 33 * 16;   // 137280 B
    (void)hipFuncSetAttribute((const void*)k_conv,
                              hipFuncAttributeMaxDynamicSharedMemorySize, lds);

    k_wt<<<dim3(768), dim3(256), 0, stream>>>(cw, wb);
    k_conv<<<dim3(T_ / 128, B_), dim3(NTHR), lds, stream>>>(h, wb, cb, ow, mask, ob,
                                                            out_alpha, a64);
    k_scan<<<dim3(B_), dim3(64), 0, stream>>>(a64, mask, out_tok, out_alpha,
                                              fire_t, fire_frac, blen);
    k_frames<<<dim3((unsigned)K, B_), dim3(128), 0, stream>>>(h, a64, fire_t, fire_frac,
                                                              blen, out_ac, (int)K);
}